// Round 4
// baseline (178.592 us; speedup 1.0000x reference)
//
#include <hip/hip_runtime.h>
#include <math.h>

#define N 4096
#define B 2048
#define RANK 4
#define ALPHA 0.8862269254527580f   // sqrt(pi)/2
#define INV_N (1.0f / 4096.0f)

#define TR 64                       // tile rows per block
#define TC 256                      // tile cols per block
#define NSPLIT (N / TR)             // 64 fp32 partial splits
#define CSTRIPES (B / TC)           // 8 col-stripes
#define NBLK (NSPLIT * CSTRIPES)    // 512 blocks
#define PLANE (5 * B)               // one split = [5][B] floats
#define RPB3 4                      // rows per block, update kernel

typedef float vf4 __attribute__((ext_vector_type(4)));

// Branchless Winitzki erf (max abs err ~2.5e-4; threshold is 0.24).
__device__ __forceinline__ float erf_fast(float t) {
  const float A = 0.140012288f;
  const float FP = 1.2732395447f;  // 4/pi
  float t2 = t * t;
  float num = fmaf(A, t2, FP);
  float den = fmaf(A, t2, 1.0f);
  float r = t2 * num * __builtin_amdgcn_rcpf(den);
  float e = __expf(-r);
  float s = __builtin_amdgcn_sqrtf(fmaxf(1.0f - e, 0.0f));
  return copysignf(s, t);
}

// ---------------------------------------------------------------------------
// Kernel A: phi + rank-4(+z) partial reduction, 2D-tiled, PLUS last-block
// finalization per column-stripe (deadlock-free: nobody waits; the 64th
// arriving block in each stripe does the 64-split sum itself).
// NOTE: cooperative launch is NOT graph-capture-safe in this harness
// (round-3: silent no-launch, zero output) — this pattern replaces it.
// 512 blocks (64 row-groups x 8 col-stripes) x 512 thr.
// ---------------------------------------------------------------------------
__global__ __launch_bounds__(512) void k_phi_fin(
    const float* __restrict__ h, const float* __restrict__ v,
    const float* __restrict__ z, float* __restrict__ partials,
    float* __restrict__ sfin, float* __restrict__ y,
    unsigned int* __restrict__ cnt) {
  __shared__ __align__(16) float red[5][8][TC];
  __shared__ unsigned int sticket;
  const int tid = threadIdx.x;
  const int l = tid & 63;
  const int g = tid >> 6;           // wave index, 0..7
  const int rg = blockIdx.x >> 3;   // row-group, 0..63
  const int cs = blockIdx.x & 7;    // col-stripe, 0..7
  const int r0 = rg * TR + g * 8;   // this wave's first row
  const int c0 = cs * TC;

  // ---- Phase 1: phi + rank-4(+z) partial reduction over the tile ----------
  vf4 a0 = {0.f, 0.f, 0.f, 0.f};
  vf4 a1 = a0, a2 = a0, a3 = a0, a4 = a0;

  const float* hp = h + (size_t)r0 * B + c0 + l * 4;
#pragma unroll
  for (int r = 0; r < 8; ++r) {
    const vf4 hv = *(const vf4*)(hp + (size_t)r * B);
    vf4 p;
    p.x = erf_fast(ALPHA * hv.x);
    p.y = erf_fast(ALPHA * hv.y);
    p.z = erf_fast(ALPHA * hv.z);
    p.w = erf_fast(ALPHA * hv.w);
    const int row = __builtin_amdgcn_readfirstlane(r0 + r);  // wave-uniform
    const float v0 = v[row * RANK + 0];
    const float v1 = v[row * RANK + 1];
    const float v2 = v[row * RANK + 2];
    const float v3 = v[row * RANK + 3];
    const float zr = z[row];
    a0.x = fmaf(v0, p.x, a0.x); a0.y = fmaf(v0, p.y, a0.y);
    a0.z = fmaf(v0, p.z, a0.z); a0.w = fmaf(v0, p.w, a0.w);
    a1.x = fmaf(v1, p.x, a1.x); a1.y = fmaf(v1, p.y, a1.y);
    a1.z = fmaf(v1, p.z, a1.z); a1.w = fmaf(v1, p.w, a1.w);
    a2.x = fmaf(v2, p.x, a2.x); a2.y = fmaf(v2, p.y, a2.y);
    a2.z = fmaf(v2, p.z, a2.z); a2.w = fmaf(v2, p.w, a2.w);
    a3.x = fmaf(v3, p.x, a3.x); a3.y = fmaf(v3, p.y, a3.y);
    a3.z = fmaf(v3, p.z, a3.z); a3.w = fmaf(v3, p.w, a3.w);
    a4.x = fmaf(zr, p.x, a4.x); a4.y = fmaf(zr, p.y, a4.y);
    a4.z = fmaf(zr, p.z, a4.z); a4.w = fmaf(zr, p.w, a4.w);
  }

  // LDS tree: wave g deposits its 5 vf4 partials (conflict-free).
  *(vf4*)&red[0][g][l * 4] = a0;
  *(vf4*)&red[1][g][l * 4] = a1;
  *(vf4*)&red[2][g][l * 4] = a2;
  *(vf4*)&red[3][g][l * 4] = a3;
  *(vf4*)&red[4][g][l * 4] = a4;
  __syncthreads();

  // 5*TC = 1280 outputs, 512 threads: o = tid, tid+512, tid+1024(<256 only).
  for (int o = tid; o < 5 * TC; o += 512) {
    const int p = o >> 8;          // TC == 256
    const int c = o & (TC - 1);
    float s = 0.f;
#pragma unroll
    for (int g2 = 0; g2 < 8; ++g2) s += red[p][g2][c];
    partials[(size_t)rg * PLANE + p * B + c0 + c] = s;
  }

  // ---- Arrival protocol: device-scope release, then per-stripe ticket -----
  __threadfence();                  // each thread: own partials stores visible
  __syncthreads();                  // all threads' fences done before ticket
  if (tid == 0) sticket = atomicAdd(&cnt[cs], 1u);
  __syncthreads();                  // broadcast ticket; also orders red reuse
  if (sticket != NSPLIT - 1) return;

  // ---- Last block of stripe cs: 64-split sum -> sfin[4][stripe] + y -------
  __threadfence();                  // acquire: see all stripes' partials
  // Two-level: wave g sums splits 8g..8g+7; lane l owns cols l*4..l*4+3 of
  // each plane k. 40 vf4 LLC loads per lane, then 8-way LDS tree (reuses red;
  // safe: all phase-1 red reads completed before the ticket __syncthreads).
#pragma unroll
  for (int k = 0; k < 5; ++k) {
    const float* pp = partials + (size_t)(g * 8) * PLANE + k * B + c0 + l * 4;
    vf4 s = {0.f, 0.f, 0.f, 0.f};
#pragma unroll
    for (int sp = 0; sp < 8; ++sp)
      s += *(const vf4*)(pp + (size_t)sp * PLANE);
    *(vf4*)&red[k][g][l * 4] = s;
  }
  __syncthreads();
  for (int o = tid; o < 5 * TC; o += 512) {
    const int p = o >> 8;
    const int c = o & (TC - 1);
    float s = 0.f;
#pragma unroll
    for (int g2 = 0; g2 < 8; ++g2) s += red[p][g2][c];
    if (p < RANK)
      sfin[p * B + c0 + c] = s;
    else
      y[c0 + c] = s * INV_N;       // y = (z.T @ phi) / N
  }
}

// ---------------------------------------------------------------------------
// Kernel B: h_new[n][b] = (sum_r u[n][r]*sfin[r][b])/N + m[n]*x[b]
// (DT/TAU = 1 -> h cancels exactly; h is never read.)
// 1024 blocks x 256 thr; block owns 4 whole rows = 32 KB contiguous
// nontemporal store slab. Thread t owns cols 4t and 4t+1024.
// ---------------------------------------------------------------------------
__global__ __launch_bounds__(256) void k_update(
    const float* __restrict__ sfin, const float* __restrict__ u,
    const float* __restrict__ m, const float* __restrict__ x,
    float* __restrict__ hnew) {
  const int tid = threadIdx.x;
  const int row0 = blockIdx.x * RPB3;
  const int c0 = tid * 4;

  const vf4 sA0 = *(const vf4*)(sfin + 0 * B + c0);
  const vf4 sA1 = *(const vf4*)(sfin + 1 * B + c0);
  const vf4 sA2 = *(const vf4*)(sfin + 2 * B + c0);
  const vf4 sA3 = *(const vf4*)(sfin + 3 * B + c0);
  const vf4 xa  = *(const vf4*)(x + c0);
  const vf4 sB0 = *(const vf4*)(sfin + 0 * B + c0 + 1024);
  const vf4 sB1 = *(const vf4*)(sfin + 1 * B + c0 + 1024);
  const vf4 sB2 = *(const vf4*)(sfin + 2 * B + c0 + 1024);
  const vf4 sB3 = *(const vf4*)(sfin + 3 * B + c0 + 1024);
  const vf4 xb  = *(const vf4*)(x + c0 + 1024);

  float* op = hnew + (size_t)row0 * B + c0;
#pragma unroll
  for (int i = 0; i < RPB3; ++i) {
    const int n = row0 + i;
    const vf4 uv = *(const vf4*)(u + (size_t)n * RANK);
    const float mv = m[n];
    vf4 oA, oB;
    oA.x = fmaf(mv, xa.x,
                (sA0.x * uv.x + sA1.x * uv.y + sA2.x * uv.z + sA3.x * uv.w) * INV_N);
    oA.y = fmaf(mv, xa.y,
                (sA0.y * uv.x + sA1.y * uv.y + sA2.y * uv.z + sA3.y * uv.w) * INV_N);
    oA.z = fmaf(mv, xa.z,
                (sA0.z * uv.x + sA1.z * uv.y + sA2.z * uv.z + sA3.z * uv.w) * INV_N);
    oA.w = fmaf(mv, xa.w,
                (sA0.w * uv.x + sA1.w * uv.y + sA2.w * uv.z + sA3.w * uv.w) * INV_N);
    oB.x = fmaf(mv, xb.x,
                (sB0.x * uv.x + sB1.x * uv.y + sB2.x * uv.z + sB3.x * uv.w) * INV_N);
    oB.y = fmaf(mv, xb.y,
                (sB0.y * uv.x + sB1.y * uv.y + sB2.y * uv.z + sB3.y * uv.w) * INV_N);
    oB.z = fmaf(mv, xb.z,
                (sB0.z * uv.x + sB1.z * uv.y + sB2.z * uv.z + sB3.z * uv.w) * INV_N);
    oB.w = fmaf(mv, xb.w,
                (sB0.w * uv.x + sB1.w * uv.y + sB2.w * uv.z + sB3.w * uv.w) * INV_N);
    __builtin_nontemporal_store(oA, (vf4*)(op + (size_t)i * B));
    __builtin_nontemporal_store(oB, (vf4*)(op + (size_t)i * B + 1024));
  }
}

// ---------------------------------------------------------------------------
extern "C" void kernel_launch(void* const* d_in, const int* in_sizes, int n_in,
                              void* d_out, int out_size, void* d_ws,
                              size_t ws_size, hipStream_t stream) {
  const float* x = (const float*)d_in[0];  // [1, B]
  const float* h = (const float*)d_in[1];  // [N, B]
  const float* m = (const float*)d_in[2];  // [N, 1]
  const float* u = (const float*)d_in[3];  // [N, RANK]
  const float* v = (const float*)d_in[4];  // [N, RANK]
  const float* z = (const float*)d_in[5];  // [N, 1]

  float* y = (float*)d_out;            // output 0: y [1, B]
  float* hnew = (float*)d_out + B;     // output 1: h_new [N, B]

  float* partials = (float*)d_ws;                    // [64][5][B] fp32, 2.62 MB
  float* sfin = partials + (size_t)NSPLIT * PLANE;   // [RANK][B] fp32, 32 KB
  unsigned int* cnt = (unsigned int*)(sfin + RANK * B);  // [8] tickets

  // Workspace is poisoned each iteration -> re-zero the tickets (32 B).
  hipMemsetAsync(cnt, 0, CSTRIPES * sizeof(unsigned int), stream);
  k_phi_fin<<<NBLK, 512, 0, stream>>>(h, v, z, partials, sfin, y, cnt);
  k_update<<<N / RPB3, 256, 0, stream>>>(sfin, u, m, x, hnew);
}

// Round 5
// 101.063 us; speedup vs baseline: 1.7671x; 1.7671x over previous
//
#include <hip/hip_runtime.h>
#include <math.h>

#define N 4096
#define B 2048
#define RANK 4
#define ALPHA 0.8862269254527580f   // sqrt(pi)/2
#define INV_N (1.0f / 4096.0f)

#define NSPLIT 16                   // partial splits (256 rows each)
#define PLANE (5 * B)               // one split = [5][B] floats
// k1 grid: 16 row-groups x 16 col-stripes = 256 blocks x 1024 thr
//   -> 1 block/CU x 16 waves = 16 waves/CU (same as proven R2 config)
// k2 grid: 64 row-groups x 8 col-stripes = 512 blocks x 512 thr

typedef float vf4 __attribute__((ext_vector_type(4)));

// Branchless Winitzki erf (max abs err ~2.5e-4; threshold is 0.24).
__device__ __forceinline__ float erf_fast(float t) {
  const float A = 0.140012288f;
  const float FP = 1.2732395447f;  // 4/pi
  float t2 = t * t;
  float num = fmaf(A, t2, FP);
  float den = fmaf(A, t2, 1.0f);
  float r = t2 * num * __builtin_amdgcn_rcpf(den);
  float e = __expf(-r);
  float s = __builtin_amdgcn_sqrtf(fmaxf(1.0f - e, 0.0f));
  return copysignf(s, t);
}

// ---------------------------------------------------------------------------
// Kernel 1: phi + rank-4(+z) partial reduction -> partials[16][5][B].
// 256 blocks (16 rg x 16 cs) x 1024 thr. Block owns 256 rows x 128 cols.
// Wave w owns 16 rows; lanes split: hf = l>>5 picks odd/even row of a pair,
// (l&31) picks the vf4 column -> each load inst covers 2 rows x 512 B
// contiguous. 16-wave LDS tree (80 KB) -> only 655 KB of global partials.
// No fences/atomics: consumers are in the next kernel (stream-ordered).
// ---------------------------------------------------------------------------
__global__ __launch_bounds__(1024) void k_phi_part(
    const float* __restrict__ h, const float* __restrict__ v,
    const float* __restrict__ z, float* __restrict__ partials) {
  __shared__ __align__(16) float red[5][16][2][128];  // 80 KB
  const int tid = threadIdx.x;
  const int l = tid & 63;
  const int w = tid >> 6;            // wave, 0..15
  const int rg = blockIdx.x >> 4;    // row-group, 0..15
  const int cs = blockIdx.x & 15;    // col-stripe, 0..15
  const int hf = l >> 5;             // row-half within pair
  const int lc = (l & 31) * 4;       // col offset within stripe
  const int c0 = cs * 128;
  const int rbase = rg * 256 + w * 16 + hf;  // this lane's first row

  vf4 a0 = {0.f, 0.f, 0.f, 0.f};
  vf4 a1 = a0, a2 = a0, a3 = a0, a4 = a0;

  const float* hp = h + (size_t)rbase * B + c0 + lc;
#pragma unroll
  for (int i = 0; i < 8; ++i) {      // 8 row-pairs = 16 rows per wave
    const int row = rbase + 2 * i;
    const vf4 hv = *(const vf4*)(hp + (size_t)(2 * i) * B);
    const vf4 vv = *(const vf4*)(v + (size_t)row * RANK);  // half-wave shared
    const float zr = z[row];
    vf4 p;
    p.x = erf_fast(ALPHA * hv.x);
    p.y = erf_fast(ALPHA * hv.y);
    p.z = erf_fast(ALPHA * hv.z);
    p.w = erf_fast(ALPHA * hv.w);
    a0.x = fmaf(vv.x, p.x, a0.x); a0.y = fmaf(vv.x, p.y, a0.y);
    a0.z = fmaf(vv.x, p.z, a0.z); a0.w = fmaf(vv.x, p.w, a0.w);
    a1.x = fmaf(vv.y, p.x, a1.x); a1.y = fmaf(vv.y, p.y, a1.y);
    a1.z = fmaf(vv.y, p.z, a1.z); a1.w = fmaf(vv.y, p.w, a1.w);
    a2.x = fmaf(vv.z, p.x, a2.x); a2.y = fmaf(vv.z, p.y, a2.y);
    a2.z = fmaf(vv.z, p.z, a2.z); a2.w = fmaf(vv.z, p.w, a2.w);
    a3.x = fmaf(vv.w, p.x, a3.x); a3.y = fmaf(vv.w, p.y, a3.y);
    a3.z = fmaf(vv.w, p.z, a3.z); a3.w = fmaf(vv.w, p.w, a3.w);
    a4.x = fmaf(zr, p.x, a4.x); a4.y = fmaf(zr, p.y, a4.y);
    a4.z = fmaf(zr, p.z, a4.z); a4.w = fmaf(zr, p.w, a4.w);
  }

  // LDS tree deposit (conflict-free: 16 B/lane, consecutive).
  *(vf4*)&red[0][w][hf][lc] = a0;
  *(vf4*)&red[1][w][hf][lc] = a1;
  *(vf4*)&red[2][w][hf][lc] = a2;
  *(vf4*)&red[3][w][hf][lc] = a3;
  *(vf4*)&red[4][w][hf][lc] = a4;
  __syncthreads();

  // 5 planes x 128 cols = 640 outputs; 32-way sum each.
  if (tid < 5 * 128) {
    const int p = tid >> 7;
    const int c = tid & 127;
    float s = 0.f;
#pragma unroll
    for (int w2 = 0; w2 < 16; ++w2) {
      s += red[p][w2][0][c];
      s += red[p][w2][1][c];
    }
    partials[(size_t)rg * PLANE + p * B + c0 + c] = s;
  }
}

// ---------------------------------------------------------------------------
// Kernel 2: fold 16 splits (64 KB L2 reads/block, ~1 us/CU) then write h_new.
// 512 blocks (64 rg x 8 cs) x 512 thr; block owns 64 rows x 256 cols.
// Phase A: thread (p, hf, cv) sums 8 splits of plane p, cols cv -> LDS.
// rg==0 blocks also fold plane 4 -> y. Phase B: wave g writes its 8 rows
// as 1 KB contiguous nontemporal stores using the LDS sums + u/m scalars.
// (DT/TAU = 1 -> h cancels exactly; h is never read here.)
// ---------------------------------------------------------------------------
__global__ __launch_bounds__(512) void k_red_update(
    const float* __restrict__ partials, const float* __restrict__ u,
    const float* __restrict__ m, const float* __restrict__ x,
    float* __restrict__ y, float* __restrict__ hnew) {
  __shared__ __align__(16) float redA[4][2][256];  // 8 KB
  __shared__ __align__(16) float redY[2][256];     // 2 KB
  const int tid = threadIdx.x;
  const int rg = blockIdx.x >> 3;   // row-group, 0..63
  const int cs = blockIdx.x & 7;    // col-stripe, 0..7
  const int c0 = cs * 256;

  // ---- Phase A: planes 0..3, 16 splits -> redA[4][2][256] -----------------
  {
    const int p = tid >> 7;          // plane 0..3
    const int rem = tid & 127;
    const int hf = rem >> 6;         // split-half 0..1
    const int cv = (rem & 63) * 4;   // vf4 col offset
    const float* pp = partials + (size_t)(hf * 8) * PLANE + p * B + c0 + cv;
    vf4 sA = {0.f, 0.f, 0.f, 0.f};
    vf4 sB = sA;
#pragma unroll
    for (int sp = 0; sp < 8; sp += 2) {
      sA += *(const vf4*)(pp + (size_t)sp * PLANE);
      sB += *(const vf4*)(pp + (size_t)(sp + 1) * PLANE);
    }
    sA += sB;
    *(vf4*)&redA[p][hf][cv] = sA;
  }
  // ---- Phase A': plane 4 (y) for rg==0 blocks -----------------------------
  if (rg == 0 && tid < 128) {
    const int hf = tid >> 6;
    const int cv = (tid & 63) * 4;
    const float* pp = partials + (size_t)(hf * 8) * PLANE + 4 * B + c0 + cv;
    vf4 s = {0.f, 0.f, 0.f, 0.f};
#pragma unroll
    for (int sp = 0; sp < 8; ++sp)
      s += *(const vf4*)(pp + (size_t)sp * PLANE);
    *(vf4*)&redY[hf][cv] = s;
  }
  __syncthreads();

  if (rg == 0 && tid < 64) {
    vf4 yy = *(const vf4*)&redY[0][tid * 4] + *(const vf4*)&redY[1][tid * 4];
    yy *= INV_N;                     // y = (z.T @ phi) / N
    *(vf4*)(y + c0 + tid * 4) = yy;
  }

  // ---- Phase B: h_new[n][b] = (sum_r u[n][r]*s_r[b])/N + m[n]*x[b] --------
  const int g = tid >> 6;            // wave, 0..7
  const int l = tid & 63;
  const int lc = l * 4;
  const vf4 s0 = *(const vf4*)&redA[0][0][lc] + *(const vf4*)&redA[0][1][lc];
  const vf4 s1 = *(const vf4*)&redA[1][0][lc] + *(const vf4*)&redA[1][1][lc];
  const vf4 s2 = *(const vf4*)&redA[2][0][lc] + *(const vf4*)&redA[2][1][lc];
  const vf4 s3 = *(const vf4*)&redA[3][0][lc] + *(const vf4*)&redA[3][1][lc];
  const vf4 xa = *(const vf4*)(x + c0 + lc);

  const int r0 = rg * 64 + g * 8;
  float* op = hnew + (size_t)r0 * B + c0 + lc;
#pragma unroll
  for (int r = 0; r < 8; ++r) {
    const int row = __builtin_amdgcn_readfirstlane(r0 + r);  // wave-uniform
    const vf4 uv = *(const vf4*)(u + (size_t)row * RANK);
    const float mv = m[row];
    vf4 o;
    o.x = fmaf(mv, xa.x,
               (s0.x * uv.x + s1.x * uv.y + s2.x * uv.z + s3.x * uv.w) * INV_N);
    o.y = fmaf(mv, xa.y,
               (s0.y * uv.x + s1.y * uv.y + s2.y * uv.z + s3.y * uv.w) * INV_N);
    o.z = fmaf(mv, xa.z,
               (s0.z * uv.x + s1.z * uv.y + s2.z * uv.z + s3.z * uv.w) * INV_N);
    o.w = fmaf(mv, xa.w,
               (s0.w * uv.x + s1.w * uv.y + s2.w * uv.z + s3.w * uv.w) * INV_N);
    __builtin_nontemporal_store(o, (vf4*)(op + (size_t)r * B));
  }
}

// ---------------------------------------------------------------------------
extern "C" void kernel_launch(void* const* d_in, const int* in_sizes, int n_in,
                              void* d_out, int out_size, void* d_ws,
                              size_t ws_size, hipStream_t stream) {
  const float* x = (const float*)d_in[0];  // [1, B]
  const float* h = (const float*)d_in[1];  // [N, B]
  const float* m = (const float*)d_in[2];  // [N, 1]
  const float* u = (const float*)d_in[3];  // [N, RANK]
  const float* v = (const float*)d_in[4];  // [N, RANK]
  const float* z = (const float*)d_in[5];  // [N, 1]

  float* y = (float*)d_out;            // output 0: y [1, B]
  float* hnew = (float*)d_out + B;     // output 1: h_new [N, B]

  float* partials = (float*)d_ws;      // [16][5][B] fp32, 655 KB

  k_phi_part<<<256, 1024, 0, stream>>>(h, v, z, partials);
  k_red_update<<<512, 512, 0, stream>>>(partials, u, m, x, y, hnew);
}